// Round 12
// baseline (96.250 us; speedup 1.0000x reference)
//
#include <hip/hip_runtime.h>
#include <math.h>

#define B_DIM 2
#define C_DIM 256
#define N_TOK 4096      // 16*16*16
#define HEADS 4
#define HD 64
#define GROUPS 8
#define CPG (C_DIM / GROUPS)   // 32
#define EPS 1e-5f
#define PSB 72          // padded bf16 LDS row stride (GEMM kernels)
#define QK_SCALE 0.180336880f  // 0.125 * log2(e), folded into Q
#define KSPLIT 4
#define NKT (N_TOK / 64)       // 64 key tiles total
#define QBLK 256               // queries per attention block (8 waves x 2 frags x 16 q)

typedef __bf16 bf16x8 __attribute__((ext_vector_type(8)));
typedef float  f32x4  __attribute__((ext_vector_type(4)));
typedef unsigned short u16x4v __attribute__((ext_vector_type(4)));
typedef unsigned short u16x8v __attribute__((ext_vector_type(8)));

__device__ __forceinline__ unsigned short f2bf(float f) {
    return __builtin_bit_cast(unsigned short, (__bf16)f);
}
__device__ __forceinline__ float bf2f(unsigned short u) {
    return (float)__builtin_bit_cast(__bf16, u);
}
// raw v_exp_f32 (2^x); inputs bounded so no OCML fixup needed
__device__ __forceinline__ float exp2_fast(float x) { return __builtin_amdgcn_exp2f(x); }

// async global->LDS, 16B per lane, wave-uniform LDS base (linear dest)
__device__ __forceinline__ void gload16(const unsigned short* g, unsigned short* l) {
    __builtin_amdgcn_global_load_lds(
        (const __attribute__((address_space(1))) unsigned int*)g,
        (__attribute__((address_space(3))) unsigned int*)l, 16, 0, 0);
}

// K-staging row permutation: [b5 b4 b3 b2 b1 b0] -> [b5 b3 b2 b4 b1 b0].
// Makes the S^T output registers exactly the PV B-fragment.
__device__ __forceinline__ int kperm(int r) {
    return (r & 0x23) | ((r & 0x0C) << 1) | ((r & 0x10) >> 2);
}

// ---------------------------------------------------------------------------
// Kernel 1: GroupNorm partial sums. 1024 blocks (16 groups x 64 chunks).
__global__ __launch_bounds__(256) void gn_part_kernel(const float* __restrict__ x,
                                                      float* __restrict__ partials) {
    const int bg = blockIdx.x >> 6, ch = blockIdx.x & 63;
    const float4* p = (const float4*)(x + (size_t)bg * CPG * N_TOK) + ch * 512;
    float s = 0.f, ss = 0.f;
#pragma unroll
    for (int r = 0; r < 2; ++r) {
        float4 v = p[threadIdx.x + (r << 8)];
        s  += v.x + v.y + v.z + v.w;
        ss += v.x * v.x + v.y * v.y + v.z * v.z + v.w * v.w;
    }
#pragma unroll
    for (int off = 32; off > 0; off >>= 1) {
        s  += __shfl_down(s, off);
        ss += __shfl_down(ss, off);
    }
    __shared__ float ls[4], lss[4];
    const int lane = threadIdx.x & 63, wid = threadIdx.x >> 6;
    if (lane == 0) { ls[wid] = s; lss[wid] = ss; }
    __syncthreads();
    if (threadIdx.x == 0) {
        partials[blockIdx.x * 2 + 0] = ls[0] + ls[1] + ls[2] + ls[3];
        partials[blockIdx.x * 2 + 1] = lss[0] + lss[1] + lss[2] + lss[3];
    }
}

// ---------------------------------------------------------------------------
// Kernel 2: fused GroupNorm finalize + apply + QKV GEMM, bf16 MFMA.
// 128x128 tile, 512 threads (8 waves = 4 o-groups x 2 n-groups), 4 K-chunks.
// q,k out: [(s*B+b)*HEADS+h][n][d] bf16 (q pre-scaled by QK_SCALE)
// v   out: [b*HEADS+h][d][n] bf16
__global__ __launch_bounds__(512) void qkv_gemm_kernel(
    const float* __restrict__ x, const float* __restrict__ partials,
    const float* __restrict__ norm_w, const float* __restrict__ norm_b,
    const float* __restrict__ qkv_w, const float* __restrict__ qkv_b,
    unsigned short* __restrict__ qkvb) {
    __shared__ unsigned short Ws[128][PSB];  // [o][c] bf16
    __shared__ unsigned short Xt[128][PSB];  // [n][c] bf16 (transposed xn)
    __shared__ float stat_s[GROUPS][2];
    const int n0 = blockIdx.x * 128;
    const int o0 = blockIdx.y * 128;
    const int b  = blockIdx.z;
    const int tid = threadIdx.x;
    const int lane = tid & 63, wid = tid >> 6;
    const int lo = lane & 15, hi = lane >> 4;
    const int wo = wid >> 1;          // 0..3 : o-group (32 rows)
    const int wn = wid & 1;           // 0..1 : n-group (64 cols)

    // finalize GroupNorm stats from partials (first 256 threads; cheap)
    if (tid < 256) {
        const int g = tid >> 5, sub = tid & 31;
        const float* pp = partials + (((size_t)b * GROUPS + g) * 64 + sub * 2) * 2;
        float4 v = *(const float4*)pp;
        float s = v.x + v.z, ss = v.y + v.w;
#pragma unroll
        for (int off = 16; off > 0; off >>= 1) {
            s  += __shfl_down(s, off, 32);
            ss += __shfl_down(ss, off, 32);
        }
        if (sub == 0) {
            const float inv = 1.f / (float)(CPG * N_TOK);
            float mean = s * inv;
            float var  = ss * inv - mean * mean;
            stat_s[g][0] = mean;
            stat_s[g][1] = rsqrtf(var + EPS);
        }
    }
    __syncthreads();

    f32x4 acc[2][4] = {};   // acc[f][nb][i]: o = o0+wo*32+f*16+hi*4+i, n = n0+wn*64+nb*16+lo
    for (int k0 = 0; k0 < C_DIM; k0 += 64) {
        // stage Ws: 128 o-rows x 64 c (f32 -> bf16)
#pragma unroll
        for (int r = 0; r < 4; ++r) {
            int idx = tid + (r << 9);
            int row = idx >> 4, col4 = (idx & 15) << 2;
            float4 wv = *(const float4*)(qkv_w + (size_t)(o0 + row) * C_DIM + k0 + col4);
            u16x4v o;
            o[0] = f2bf(wv.x); o[1] = f2bf(wv.y); o[2] = f2bf(wv.z); o[3] = f2bf(wv.w);
            *(u16x4v*)&Ws[row][col4] = o;
        }
        // stage Xt: 64 c-rows x 128 n, normalized, transposed into [n][c]
#pragma unroll
        for (int r = 0; r < 4; ++r) {
            int idx = tid + (r << 9);
            int crow = idx >> 5, col4 = (idx & 31) << 2;
            int c = k0 + crow;
            int g = c >> 5;
            float ww = norm_w[c] * stat_s[g][1];
            float bb = norm_b[c] - stat_s[g][0] * ww;
            float4 v = *(const float4*)(x + ((size_t)b * C_DIM + c) * N_TOK + n0 + col4);
            Xt[col4 + 0][crow] = f2bf(v.x * ww + bb);
            Xt[col4 + 1][crow] = f2bf(v.y * ww + bb);
            Xt[col4 + 2][crow] = f2bf(v.z * ww + bb);
            Xt[col4 + 3][crow] = f2bf(v.w * ww + bb);
        }
        __syncthreads();
#pragma unroll
        for (int ck = 0; ck < 2; ++ck) {
            bf16x8 aw[2];
#pragma unroll
            for (int f = 0; f < 2; ++f)
                aw[f] = *(const bf16x8*)&Ws[wo * 32 + f * 16 + lo][ck * 32 + hi * 8];
#pragma unroll
            for (int nb = 0; nb < 4; ++nb) {
                bf16x8 xb = *(const bf16x8*)&Xt[wn * 64 + nb * 16 + lo][ck * 32 + hi * 8];
                acc[0][nb] = __builtin_amdgcn_mfma_f32_16x16x32_bf16(aw[0], xb, acc[0][nb], 0, 0, 0);
                acc[1][nb] = __builtin_amdgcn_mfma_f32_16x16x32_bf16(aw[1], xb, acc[1][nb], 0, 0, 0);
            }
        }
        __syncthreads();
    }

    const size_t plane = (size_t)N_TOK * HD;
#pragma unroll
    for (int f = 0; f < 2; ++f) {
        const int o_base = o0 + wo * 32 + f * 16;     // multiple of 16; one head group
        const int sidx = o_base >> 8;                 // 0=q, 1=k, 2=v
        const int head = (o_base >> 6) & 3;
        const int od = (o_base & 63) + hi * 4;        // d within head (+i)
        float bias[4];
#pragma unroll
        for (int i = 0; i < 4; ++i) bias[i] = qkv_b[o_base + hi * 4 + i];

        if (sidx < 2) {
            const float sc = (sidx == 0) ? QK_SCALE : 1.0f;
            unsigned short* base = qkvb + ((size_t)(sidx * B_DIM + b) * HEADS + head) * plane;
#pragma unroll
            for (int nb = 0; nb < 4; ++nb) {
                int n = n0 + wn * 64 + nb * 16 + lo;
                u16x4v o;
#pragma unroll
                for (int i = 0; i < 4; ++i) o[i] = f2bf((acc[f][nb][i] + bias[i]) * sc);
                *(u16x4v*)(base + (size_t)n * HD + od) = o;
            }
        } else {
            unsigned short* base = qkvb + (size_t)2 * B_DIM * HEADS * plane
                                 + ((size_t)b * HEADS + head) * plane;
#pragma unroll
            for (int nb = 0; nb < 4; ++nb) {
                int n = n0 + wn * 64 + nb * 16 + lo;
#pragma unroll
                for (int i = 0; i < 4; ++i)
                    base[(size_t)(od + i) * N_TOK + n] = f2bf(acc[f][nb][i] + bias[i]);
            }
        }
    }
}

// ---------------------------------------------------------------------------
// Kernel 3: bf16 MFMA flash attention, swapped-operand (S^T), K-split x4.
// 8 waves x 2 q-frags x 16 q = QBLK 256. K/V LDS fragments are read ONCE and
// feed both frags' MFMAs (halves LDS-read traffic vs 1-frag). global_load_lds
// dbuf staging (linear dest, pre-swizzled source), 1 barrier/tile.
__global__ __launch_bounds__(512, 4) void attn_kernel(const unsigned short* __restrict__ qkvb,
                                                      unsigned short* __restrict__ obuf,
                                                      float* __restrict__ rbuf) {
    const int bh = blockIdx.x & 7;            // b*HEADS + head
    const int ks = (blockIdx.x >> 3) & 3;     // key-split quarter
    const int q0 = (blockIdx.x >> 5) * QBLK;
    const size_t plane = (size_t)N_TOK * HD;
    const unsigned short* Qg  = qkvb + (size_t)bh * plane;
    const unsigned short* Kg  = qkvb + (size_t)(B_DIM * HEADS + bh) * plane;
    const unsigned short* Vtg = qkvb + (size_t)2 * B_DIM * HEADS * plane + (size_t)bh * plane;

    __shared__ unsigned short Ks[2][64][64];  // [buf][perm key row][d] (col-swizzled)
    __shared__ unsigned short Vt[2][64][64];  // [buf][d][key]          (col-swizzled)

    const int tid  = threadIdx.x;
    const int lane = tid & 63;
    const int wid  = tid >> 6;                // 0..7
    const int lo   = lane & 15;
    const int hi   = lane >> 4;

    // Q fragments: frag f covers q = q0 + wid*32 + f*16 + lo, d-chunks c*32+hi*8
    bf16x8 qf[2][2];
#pragma unroll
    for (int f = 0; f < 2; ++f)
#pragma unroll
        for (int c = 0; c < 2; ++c)
            qf[f][c] = *(const bf16x8*)(Qg + (size_t)(q0 + wid * 32 + f * 16 + lo) * HD
                                            + c * 32 + hi * 8);

    // staging geometry: 512 threads cover the 64x64 tile in ONE K + ONE V DMA
    // per thread. thread -> row = tid>>3, 16B chunk = tid&7; source pre-swizzled.
    const int srow = tid >> 3, sblk = tid & 7;
    const int c16s = (sblk ^ (srow & 7)) * 8;
    const int krow = kperm(srow);
    // swizzled read column (elements) per d-chunk c: ((c*4+hi)^(lo&7))*8
    int rcol[2];
#pragma unroll
    for (int c = 0; c < 2; ++c) rcol[c] = (((c * 4 + hi) ^ (lo & 7)) << 3);

#define STAGE_KV(bufi, kbase)                                                          \
    do {                                                                               \
        gload16(Kg + (size_t)((kbase) + krow) * HD + c16s, &Ks[bufi][wid * 8][0]);     \
        gload16(Vtg + (size_t)srow * N_TOK + (kbase) + c16s, &Vt[bufi][wid * 8][0]);   \
    } while (0)

    const int kt0 = ks * (NKT / KSPLIT), ktE = kt0 + NKT / KSPLIT;

    f32x4 acc[2][4] = {};   // acc[f][db][i] = O^T[d=db*16+hi*4+i][q of frag f]
    float m[2] = {-1e30f, -1e30f}, l[2] = {0.f, 0.f};

    STAGE_KV(0, kt0 * 64);
    __syncthreads();   // drains the DMA (vmcnt 0) + barrier

    for (int kt = kt0; kt < ktE; ++kt) {
        const int cur = kt & 1;
        if (kt + 1 < ktE) STAGE_KV(cur ^ 1, (kt + 1) * 64);

        // S^T = K Q^T for BOTH frags; each K fragment read once, used twice.
        f32x4 s4[2][4] = {};
        __builtin_amdgcn_s_setprio(1);
#pragma unroll
        for (int kb = 0; kb < 4; ++kb)
#pragma unroll
            for (int c = 0; c < 2; ++c) {
                bf16x8 kf = *(const bf16x8*)&Ks[cur][kb * 16 + lo][rcol[c]];
                s4[0][kb] = __builtin_amdgcn_mfma_f32_16x16x32_bf16(kf, qf[0][c], s4[0][kb], 0, 0, 0);
                s4[1][kb] = __builtin_amdgcn_mfma_f32_16x16x32_bf16(kf, qf[1][c], s4[1][kb], 0, 0, 0);
            }
        __builtin_amdgcn_s_setprio(0);

        // softmax per frag (lane-local; cross-lane only in rare rescale branch)
        bf16x8 pf[2][2];
#pragma unroll
        for (int f = 0; f < 2; ++f) {
            float r0 = fmaxf(fmaxf(fmaxf(s4[f][0][0], s4[f][0][1]), s4[f][0][2]), s4[f][0][3]);
            float r1 = fmaxf(fmaxf(fmaxf(s4[f][1][0], s4[f][1][1]), s4[f][1][2]), s4[f][1][3]);
            float r2 = fmaxf(fmaxf(fmaxf(s4[f][2][0], s4[f][2][1]), s4[f][2][2]), s4[f][2][3]);
            float r3 = fmaxf(fmaxf(fmaxf(s4[f][3][0], s4[f][3][1]), s4[f][3][2]), s4[f][3][3]);
            float rm = fmaxf(fmaxf(fmaxf(r0, r1), r2), r3);

            // defer-max (T13) with LOCAL max check
            if (__any(rm > m[f] + 8.0f)) {
                float rmx = rm;
                rmx = fmaxf(rmx, __shfl_xor(rmx, 16));
                rmx = fmaxf(rmx, __shfl_xor(rmx, 32));
                const float mn = fmaxf(m[f], rmx);
                const float fi = exp2_fast(m[f] - mn);
                m[f] = mn;
                l[f] *= fi;
#pragma unroll
                for (int db = 0; db < 4; ++db)
#pragma unroll
                    for (int i = 0; i < 4; ++i) acc[f][db][i] *= fi;
            }

            float p[4][4];
#pragma unroll
            for (int kb = 0; kb < 4; ++kb)
#pragma unroll
                for (int i = 0; i < 4; ++i)
                    p[kb][i] = exp2_fast(s4[f][kb][i] - m[f]);
            // tree-sum (dep depth 4 instead of 16)
            float s01 = (p[0][0] + p[0][1]) + (p[0][2] + p[0][3]);
            float s23 = (p[1][0] + p[1][1]) + (p[1][2] + p[1][3]);
            float s45 = (p[2][0] + p[2][1]) + (p[2][2] + p[2][3]);
            float s67 = (p[3][0] + p[3][1]) + (p[3][2] + p[3][3]);
            l[f] += (s01 + s23) + (s45 + s67);

            // pack P into PV B-fragment: pf[f][c][j] = p[2c + (j>>2)][j&3]
#pragma unroll
            for (int c = 0; c < 2; ++c)
#pragma unroll
                for (int j = 0; j < 8; ++j) pf[f][c][j] = (__bf16)p[2 * c + (j >> 2)][j & 3];
        }

        // O^T += V^T P^T for BOTH frags; each V fragment read once, used twice.
        __builtin_amdgcn_s_setprio(1);
#pragma unroll
        for (int db = 0; db < 4; ++db)
#pragma unroll
            for (int c = 0; c < 2; ++c) {
                bf16x8 vf = *(const bf16x8*)&Vt[cur][db * 16 + lo][rcol[c]];
                acc[0][db] = __builtin_amdgcn_mfma_f32_16x16x32_bf16(vf, pf[0][c], acc[0][db], 0, 0, 0);
                acc[1][db] = __builtin_amdgcn_mfma_f32_16x16x32_bf16(vf, pf[1][c], acc[1][db], 0, 0, 0);
            }
        __builtin_amdgcn_s_setprio(0);

        // one barrier per tile: drains this wave's DMA (implicit vmcnt 0)
        // and guarantees all waves finished reading buf[cur].
        __syncthreads();
    }
#undef STAGE_KV

    // epilogue per frag: normalized bf16 partial O + log-sum-exp r
#pragma unroll
    for (int f = 0; f < 2; ++f) {
        float l1 = l[f] + __shfl_xor(l[f], 16);
        float lt = l1 + __shfl_xor(l1, 32);
        const float inv = 1.f / lt;
        const int n = q0 + wid * 32 + f * 16 + lo;
        unsigned short* ob = obuf + ((size_t)(ks * 8 + bh) * N_TOK + n) * HD;
#pragma unroll
        for (int db = 0; db < 4; ++db) {
            u16x4v o;
#pragma unroll
            for (int i = 0; i < 4; ++i) o[i] = f2bf(acc[f][db][i] * inv);
            *(u16x4v*)(ob + db * 16 + hi * 4) = o;
        }
        if (hi == 0)
            rbuf[(size_t)(ks * 8 + bh) * N_TOK + n] = m[f] + __builtin_amdgcn_logf(lt);
    }
}

// ---------------------------------------------------------------------------
// Kernel 4: output projection + bias + residual, bf16 MFMA.
// K-split combine fused into the h staging (reads obuf/rbuf directly).
__global__ __launch_bounds__(256) void proj_kernel(
    const unsigned short* __restrict__ obuf, const float* __restrict__ rbuf,
    const float* __restrict__ proj_w, const float* __restrict__ proj_b,
    const float* __restrict__ x, float* __restrict__ out) {
    __shared__ unsigned short Ws[64][PSB];  // [o][c]
    __shared__ unsigned short Hs[64][PSB];  // [n][c-within-head]
    const int n0 = blockIdx.x * 64;
    const int o0 = blockIdx.y * 64;
    const int b  = blockIdx.z;
    const int tid = threadIdx.x;
    const int lane = tid & 63, w = tid >> 6;
    const int lo = lane & 15, hi = lane >> 4;
    f32x4 acc[4] = {};

    for (int k0 = 0; k0 < C_DIM; k0 += 64) {
#pragma unroll
        for (int r = 0; r < 4; ++r) {
            int idx = tid + (r << 8);
            int row = idx >> 4, col4 = (idx & 15) << 2;
            float4 wv = *(const float4*)(proj_w + (size_t)(o0 + row) * C_DIM + k0 + col4);
            u16x4v o;
            o[0] = f2bf(wv.x); o[1] = f2bf(wv.y); o[2] = f2bf(wv.z); o[3] = f2bf(wv.w);
            *(u16x4v*)&Ws[row][col4] = o;
        }
        // stage h[n][k0..k0+64): head = k0>>6; combine the 4 K-split partials
        {
            const int head = k0 >> 6;
            const int bh = b * HEADS + head;
#pragma unroll
            for (int r = 0; r < 2; ++r) {
                int idx = tid + (r << 8);
                int row = idx >> 3, blk = idx & 7;   // n-row in tile, 8-d chunk
                int n = n0 + row;
                float rr[KSPLIT], M = -1e30f;
#pragma unroll
                for (int k = 0; k < KSPLIT; ++k) {
                    rr[k] = rbuf[(size_t)(k * 8 + bh) * N_TOK + n];
                    M = fmaxf(M, rr[k]);
                }
                float wk[KSPLIT], tot = 0.f;
#pragma unroll
                for (int k = 0; k < KSPLIT; ++k) { wk[k] = exp2_fast(rr[k] - M); tot += wk[k]; }
                const float inv = 1.f / tot;
                float a[8] = {};
#pragma unroll
                for (int k = 0; k < KSPLIT; ++k) {
                    u16x8v v = *(const u16x8v*)(obuf
                        + ((size_t)(k * 8 + bh) * N_TOK + n) * HD + blk * 8);
#pragma unroll
                    for (int j = 0; j < 8; ++j) a[j] += wk[k] * bf2f(v[j]);
                }
                u16x8v o;
#pragma unroll
                for (int j = 0; j < 8; ++j) o[j] = f2bf(a[j] * inv);
                *(u16x8v*)&Hs[row][blk * 8] = o;
            }
        }
        __syncthreads();
#pragma unroll
        for (int ck = 0; ck < 2; ++ck) {
            bf16x8 aw = *(const bf16x8*)&Ws[w * 16 + lo][ck * 32 + hi * 8];
#pragma unroll
            for (int nb = 0; nb < 4; ++nb)
                acc[nb] = __builtin_amdgcn_mfma_f32_16x16x32_bf16(
                    aw, *(const bf16x8*)&Hs[nb * 16 + lo][ck * 32 + hi * 8], acc[nb], 0, 0, 0);
        }
        __syncthreads();
    }

#pragma unroll
    for (int nb = 0; nb < 4; ++nb) {
#pragma unroll
        for (int i = 0; i < 4; ++i) {
            int o = o0 + w * 16 + hi * 4 + i;
            size_t addr = ((size_t)b * C_DIM + o) * N_TOK + n0 + nb * 16 + lo;
            out[addr] = acc[nb][i] + proj_b[o] + x[addr];
        }
    }
}

// ---------------------------------------------------------------------------
extern "C" void kernel_launch(void* const* d_in, const int* in_sizes, int n_in,
                              void* d_out, int out_size, void* d_ws, size_t ws_size,
                              hipStream_t stream) {
    const float* x      = (const float*)d_in[0];
    const float* norm_w = (const float*)d_in[1];
    const float* norm_b = (const float*)d_in[2];
    const float* qkv_w  = (const float*)d_in[3];
    const float* qkv_b  = (const float*)d_in[4];
    const float* proj_w = (const float*)d_in[5];
    const float* proj_b = (const float*)d_in[6];
    float* out = (float*)d_out;

    // ws: partials f32[2048] | qkvb bf16 (12.6MB)
    //   | obuf bf16 [4][8][N][HD] (16.8MB) | rbuf f32 [4][8][N] (512KB) ~= 29.9MB
    float* partials = (float*)d_ws;
    unsigned short* qkvb = (unsigned short*)(partials + 2048);
    unsigned short* obuf = qkvb + (size_t)3 * B_DIM * HEADS * N_TOK * HD;
    float* rbuf = (float*)(obuf + (size_t)KSPLIT * B_DIM * HEADS * N_TOK * HD);

    gn_part_kernel<<<B_DIM * GROUPS * 64, 256, 0, stream>>>(x, partials);
    qkv_gemm_kernel<<<dim3(N_TOK / 128, 3 * C_DIM / 128, B_DIM), 512, 0, stream>>>(
        x, partials, norm_w, norm_b, qkv_w, qkv_b, qkvb);
    attn_kernel<<<(N_TOK / QBLK) * B_DIM * HEADS * KSPLIT, 512, 0, stream>>>(qkvb, obuf, rbuf);
    proj_kernel<<<dim3(N_TOK / 64, C_DIM / 64, B_DIM), 256, 0, stream>>>(
        obuf, rbuf, proj_w, proj_b, x, out);
}

// Round 13
// 90.826 us; speedup vs baseline: 1.0597x; 1.0597x over previous
//
#include <hip/hip_runtime.h>
#include <math.h>

#define B_DIM 2
#define C_DIM 256
#define N_TOK 4096      // 16*16*16
#define HEADS 4
#define HD 64
#define GROUPS 8
#define CPG (C_DIM / GROUPS)   // 32
#define EPS 1e-5f
#define PSB 72          // padded bf16 LDS row stride (Xt staging)
#define QK_SCALE 0.180336880f  // 0.125 * log2(e), folded into Q
#define KSPLIT 4
#define NKT (N_TOK / 64)       // 64 key tiles total
#define QBLK 256               // queries per attention block (8 waves x 2 frags x 16 q)
#define NQKVW (3 * C_DIM * C_DIM)   // 196608 qkv_w elems
#define NPROJW (C_DIM * C_DIM)      // 65536 proj_w elems

typedef __bf16 bf16x8 __attribute__((ext_vector_type(8)));
typedef float  f32x4  __attribute__((ext_vector_type(4)));
typedef unsigned short u16x4v __attribute__((ext_vector_type(4)));
typedef unsigned short u16x8v __attribute__((ext_vector_type(8)));

__device__ __forceinline__ unsigned short f2bf(float f) {
    return __builtin_bit_cast(unsigned short, (__bf16)f);
}
__device__ __forceinline__ float bf2f(unsigned short u) {
    return (float)__builtin_bit_cast(__bf16, u);
}
// raw v_exp_f32 (2^x); inputs bounded so no OCML fixup needed
__device__ __forceinline__ float exp2_fast(float x) { return __builtin_amdgcn_exp2f(x); }

// async global->LDS, 16B per lane, wave-uniform LDS base (linear dest)
__device__ __forceinline__ void gload16(const unsigned short* g, unsigned short* l) {
    __builtin_amdgcn_global_load_lds(
        (const __attribute__((address_space(1))) unsigned int*)g,
        (__attribute__((address_space(3))) unsigned int*)l, 16, 0, 0);
}

// K-staging row permutation: [b5 b4 b3 b2 b1 b0] -> [b5 b3 b2 b4 b1 b0].
// Makes the S^T output registers exactly the PV B-fragment.
__device__ __forceinline__ int kperm(int r) {
    return (r & 0x23) | ((r & 0x0C) << 1) | ((r & 0x10) >> 2);
}

// ---------------------------------------------------------------------------
// Kernel 1: GroupNorm partial sums (1024 blocks) + weight f32->bf16 convert
// tail (262144 = 1024*256 elems, one per thread, coalesced).
__global__ __launch_bounds__(256) void gn_part_kernel(const float* __restrict__ x,
                                                      const float* __restrict__ qkv_w,
                                                      const float* __restrict__ proj_w,
                                                      float* __restrict__ partials,
                                                      unsigned short* __restrict__ wbf) {
    const int bg = blockIdx.x >> 6, ch = blockIdx.x & 63;
    const float4* p = (const float4*)(x + (size_t)bg * CPG * N_TOK) + ch * 512;
    float s = 0.f, ss = 0.f;
#pragma unroll
    for (int r = 0; r < 2; ++r) {
        float4 v = p[threadIdx.x + (r << 8)];
        s  += v.x + v.y + v.z + v.w;
        ss += v.x * v.x + v.y * v.y + v.z * v.z + v.w * v.w;
    }
#pragma unroll
    for (int off = 32; off > 0; off >>= 1) {
        s  += __shfl_down(s, off);
        ss += __shfl_down(ss, off);
    }
    __shared__ float ls[4], lss[4];
    const int lane = threadIdx.x & 63, wid = threadIdx.x >> 6;
    if (lane == 0) { ls[wid] = s; lss[wid] = ss; }

    // weight convert tail (no sync needed; independent outputs)
    const int widx = blockIdx.x * 256 + threadIdx.x;
    float wv = (widx < NQKVW) ? qkv_w[widx] : proj_w[widx - NQKVW];
    wbf[widx] = f2bf(wv);

    __syncthreads();
    if (threadIdx.x == 0) {
        partials[blockIdx.x * 2 + 0] = ls[0] + ls[1] + ls[2] + ls[3];
        partials[blockIdx.x * 2 + 1] = lss[0] + lss[1] + lss[2] + lss[3];
    }
}

// ---------------------------------------------------------------------------
// Kernel 2: fused GroupNorm finalize + apply + QKV GEMM, bf16 MFMA.
// 64x64 tile, 256 threads. Ws staged via global_load_lds from pre-converted
// bf16 weights (XOR-swizzled source, linear LDS dest); Xt reg-staged.
// q,k out: [(s*B+b)*HEADS+h][n][d] bf16 (q pre-scaled); v out: [b*HEADS+h][d][n]
__global__ __launch_bounds__(256) void qkv_gemm_kernel(
    const float* __restrict__ x, const float* __restrict__ partials,
    const float* __restrict__ norm_w, const float* __restrict__ norm_b,
    const unsigned short* __restrict__ wqbf, const float* __restrict__ qkv_b,
    unsigned short* __restrict__ qkvb) {
    __shared__ unsigned short Ws[64][64];   // [o][c] bf16, col-swizzled
    __shared__ unsigned short Xt[64][PSB];  // [n][c] bf16 (transposed xn)
    __shared__ float stat_s[GROUPS][2];
    const int n0 = blockIdx.x * 64;
    const int o0 = blockIdx.y * 64;
    const int b  = blockIdx.z;
    const int tid = threadIdx.x;
    const int lane = tid & 63, w = tid >> 6;
    const int lo = lane & 15, hi = lane >> 4;
    const int srow8 = lane >> 3, sblk = lane & 7;
    const int c16s = (sblk ^ srow8) * 8;    // swizzled source chunk (elements)
    // swizzled read column per d-chunk ck: ((ck*4+hi)^(lo&7))*8
    int rcol[2];
#pragma unroll
    for (int c = 0; c < 2; ++c) rcol[c] = (((c * 4 + hi) ^ (lo & 7)) << 3);

    // finalize GroupNorm stats from partials (each block, redundantly; cheap)
    {
        const int g = tid >> 5, sub = tid & 31;
        const float* pp = partials + (((size_t)b * GROUPS + g) * 64 + sub * 2) * 2;
        float4 v = *(const float4*)pp;
        float s = v.x + v.z, ss = v.y + v.w;
#pragma unroll
        for (int off = 16; off > 0; off >>= 1) {
            s  += __shfl_down(s, off, 32);
            ss += __shfl_down(ss, off, 32);
        }
        if (sub == 0) {
            const float inv = 1.f / (float)(CPG * N_TOK);
            float mean = s * inv;
            float var  = ss * inv - mean * mean;
            stat_s[g][0] = mean;
            stat_s[g][1] = rsqrtf(var + EPS);
        }
        __syncthreads();
    }

    f32x4 acc[4] = {};
    for (int k0 = 0; k0 < C_DIM; k0 += 64) {
        // Ws via DMA: 2 instrs cover 64 rows x 8 chunks (wave w -> rows i*32+w*8..+8)
#pragma unroll
        for (int i = 0; i < 2; ++i) {
            int row = i * 32 + w * 8 + srow8;
            gload16(wqbf + (size_t)(o0 + row) * C_DIM + k0 + c16s, &Ws[i * 32 + w * 8][0]);
        }
        // Xt: 64 c-rows x 64 n, normalized, transposed into [n][c]
#pragma unroll
        for (int r = 0; r < 4; ++r) {
            int idx = tid + (r << 8);
            int crow = idx >> 4, col4 = (idx & 15) << 2;
            int c = k0 + crow;
            int g = c >> 5;
            float ww = norm_w[c] * stat_s[g][1];
            float bb = norm_b[c] - stat_s[g][0] * ww;
            float4 v = *(const float4*)(x + ((size_t)b * C_DIM + c) * N_TOK + n0 + col4);
            Xt[col4 + 0][crow] = f2bf(v.x * ww + bb);
            Xt[col4 + 1][crow] = f2bf(v.y * ww + bb);
            Xt[col4 + 2][crow] = f2bf(v.z * ww + bb);
            Xt[col4 + 3][crow] = f2bf(v.w * ww + bb);
        }
        __syncthreads();   // drains DMA (vmcnt) + ds_writes (lgkm)
#pragma unroll
        for (int ck = 0; ck < 2; ++ck) {
            bf16x8 aw = *(const bf16x8*)&Ws[w * 16 + lo][rcol[ck]];
#pragma unroll
            for (int nb = 0; nb < 4; ++nb)
                acc[nb] = __builtin_amdgcn_mfma_f32_16x16x32_bf16(
                    aw, *(const bf16x8*)&Xt[nb * 16 + lo][ck * 32 + hi * 8], acc[nb], 0, 0, 0);
        }
        __syncthreads();
    }

    const int sidx = o0 >> 8;           // 0=q, 1=k, 2=v
    const int head = (o0 >> 6) & 3;
    const int od = w * 16 + hi * 4;     // d within head (+i)
    float bias[4];
#pragma unroll
    for (int i = 0; i < 4; ++i) bias[i] = qkv_b[o0 + od + i];
    const size_t plane = (size_t)N_TOK * HD;

    if (sidx < 2) {
        const float sc = (sidx == 0) ? QK_SCALE : 1.0f;
        unsigned short* base = qkvb + ((size_t)(sidx * B_DIM + b) * HEADS + head) * plane;
#pragma unroll
        for (int nb = 0; nb < 4; ++nb) {
            int n = n0 + nb * 16 + lo;
            u16x4v o;
#pragma unroll
            for (int i = 0; i < 4; ++i) o[i] = f2bf((acc[nb][i] + bias[i]) * sc);
            *(u16x4v*)(base + (size_t)n * HD + od) = o;
        }
    } else {
        unsigned short* base = qkvb + (size_t)2 * B_DIM * HEADS * plane
                             + ((size_t)b * HEADS + head) * plane;
#pragma unroll
        for (int nb = 0; nb < 4; ++nb)
#pragma unroll
            for (int i = 0; i < 4; ++i)
                base[(size_t)(od + i) * N_TOK + n0 + nb * 16 + lo] = f2bf(acc[nb][i] + bias[i]);
    }
}

// ---------------------------------------------------------------------------
// Kernel 3: bf16 MFMA flash attention (exact round-10 structure, proven 51.3us).
__global__ __launch_bounds__(512, 4) void attn_kernel(const unsigned short* __restrict__ qkvb,
                                                      unsigned short* __restrict__ obuf,
                                                      float* __restrict__ rbuf) {
    const int bh = blockIdx.x & 7;            // b*HEADS + head
    const int ks = (blockIdx.x >> 3) & 3;     // key-split quarter
    const int q0 = (blockIdx.x >> 5) * QBLK;
    const size_t plane = (size_t)N_TOK * HD;
    const unsigned short* Qg  = qkvb + (size_t)bh * plane;
    const unsigned short* Kg  = qkvb + (size_t)(B_DIM * HEADS + bh) * plane;
    const unsigned short* Vtg = qkvb + (size_t)2 * B_DIM * HEADS * plane + (size_t)bh * plane;

    __shared__ unsigned short Ks[2][64][64];  // [buf][perm key row][d] (col-swizzled)
    __shared__ unsigned short Vt[2][64][64];  // [buf][d][key]          (col-swizzled)

    const int tid  = threadIdx.x;
    const int lane = tid & 63;
    const int wid  = tid >> 6;                // 0..7
    const int lo   = lane & 15;
    const int hi   = lane >> 4;

    // Q fragments: frag f covers q = q0 + wid*32 + f*16 + lo, d-chunks c*32+hi*8
    bf16x8 qf[2][2];
#pragma unroll
    for (int f = 0; f < 2; ++f)
#pragma unroll
        for (int c = 0; c < 2; ++c)
            qf[f][c] = *(const bf16x8*)(Qg + (size_t)(q0 + wid * 32 + f * 16 + lo) * HD
                                            + c * 32 + hi * 8);

    const int srow = tid >> 3, sblk = tid & 7;
    const int c16s = (sblk ^ (srow & 7)) * 8;
    const int krow = kperm(srow);
    int rcol[2];
#pragma unroll
    for (int c = 0; c < 2; ++c) rcol[c] = (((c * 4 + hi) ^ (lo & 7)) << 3);

#define STAGE_KV(bufi, kbase)                                                          \
    do {                                                                               \
        gload16(Kg + (size_t)((kbase) + krow) * HD + c16s, &Ks[bufi][wid * 8][0]);     \
        gload16(Vtg + (size_t)srow * N_TOK + (kbase) + c16s, &Vt[bufi][wid * 8][0]);   \
    } while (0)

    const int kt0 = ks * (NKT / KSPLIT), ktE = kt0 + NKT / KSPLIT;

    f32x4 acc[2][4] = {};   // acc[f][db][i] = O^T[d=db*16+hi*4+i][q of frag f]
    float m[2] = {-1e30f, -1e30f}, l[2] = {0.f, 0.f};

    STAGE_KV(0, kt0 * 64);
    __syncthreads();   // drains the DMA (vmcnt 0) + barrier

    for (int kt = kt0; kt < ktE; ++kt) {
        const int cur = kt & 1;
        if (kt + 1 < ktE) STAGE_KV(cur ^ 1, (kt + 1) * 64);

        // S^T = K Q^T for BOTH frags; each K fragment read once, used twice.
        f32x4 s4[2][4] = {};
        __builtin_amdgcn_s_setprio(1);
#pragma unroll
        for (int kb = 0; kb < 4; ++kb)
#pragma unroll
            for (int c = 0; c < 2; ++c) {
                bf16x8 kf = *(const bf16x8*)&Ks[cur][kb * 16 + lo][rcol[c]];
                s4[0][kb] = __builtin_amdgcn_mfma_f32_16x16x32_bf16(kf, qf[0][c], s4[0][kb], 0, 0, 0);
                s4[1][kb] = __builtin_amdgcn_mfma_f32_16x16x32_bf16(kf, qf[1][c], s4[1][kb], 0, 0, 0);
            }
        __builtin_amdgcn_s_setprio(0);

        // softmax per frag (lane-local; cross-lane only in rare rescale branch)
        bf16x8 pf[2][2];
#pragma unroll
        for (int f = 0; f < 2; ++f) {
            float r0 = fmaxf(fmaxf(fmaxf(s4[f][0][0], s4[f][0][1]), s4[f][0][2]), s4[f][0][3]);
            float r1 = fmaxf(fmaxf(fmaxf(s4[f][1][0], s4[f][1][1]), s4[f][1][2]), s4[f][1][3]);
            float r2 = fmaxf(fmaxf(fmaxf(s4[f][2][0], s4[f][2][1]), s4[f][2][2]), s4[f][2][3]);
            float r3 = fmaxf(fmaxf(fmaxf(s4[f][3][0], s4[f][3][1]), s4[f][3][2]), s4[f][3][3]);
            float rm = fmaxf(fmaxf(fmaxf(r0, r1), r2), r3);

            // defer-max (T13) with LOCAL max check
            if (__any(rm > m[f] + 8.0f)) {
                float rmx = rm;
                rmx = fmaxf(rmx, __shfl_xor(rmx, 16));
                rmx = fmaxf(rmx, __shfl_xor(rmx, 32));
                const float mn = fmaxf(m[f], rmx);
                const float fi = exp2_fast(m[f] - mn);
                m[f] = mn;
                l[f] *= fi;
#pragma unroll
                for (int db = 0; db < 4; ++db)
#pragma unroll
                    for (int i = 0; i < 4; ++i) acc[f][db][i] *= fi;
            }

            float p[4][4];
            float ps = 0.f;
#pragma unroll
            for (int kb = 0; kb < 4; ++kb)
#pragma unroll
                for (int i = 0; i < 4; ++i) {
                    p[kb][i] = exp2_fast(s4[f][kb][i] - m[f]);
                    ps += p[kb][i];
                }
            l[f] += ps;

            // pack P into PV B-fragment: pf[f][c][j] = p[2c + (j>>2)][j&3]
#pragma unroll
            for (int c = 0; c < 2; ++c)
#pragma unroll
                for (int j = 0; j < 8; ++j) pf[f][c][j] = (__bf16)p[2 * c + (j >> 2)][j & 3];
        }

        // O^T += V^T P^T for BOTH frags; each V fragment read once, used twice.
        __builtin_amdgcn_s_setprio(1);
#pragma unroll
        for (int db = 0; db < 4; ++db)
#pragma unroll
            for (int c = 0; c < 2; ++c) {
                bf16x8 vf = *(const bf16x8*)&Vt[cur][db * 16 + lo][rcol[c]];
                acc[0][db] = __builtin_amdgcn_mfma_f32_16x16x32_bf16(vf, pf[0][c], acc[0][db], 0, 0, 0);
                acc[1][db] = __builtin_amdgcn_mfma_f32_16x16x32_bf16(vf, pf[1][c], acc[1][db], 0, 0, 0);
            }
        __builtin_amdgcn_s_setprio(0);

        __syncthreads();
    }
#undef STAGE_KV

    // epilogue per frag: normalized bf16 partial O + log-sum-exp r
#pragma unroll
    for (int f = 0; f < 2; ++f) {
        float l1 = l[f] + __shfl_xor(l[f], 16);
        float lt = l1 + __shfl_xor(l1, 32);
        const float inv = 1.f / lt;
        const int n = q0 + wid * 32 + f * 16 + lo;
        unsigned short* ob = obuf + ((size_t)(ks * 8 + bh) * N_TOK + n) * HD;
#pragma unroll
        for (int db = 0; db < 4; ++db) {
            u16x4v o;
#pragma unroll
            for (int i = 0; i < 4; ++i) o[i] = f2bf(acc[f][db][i] * inv);
            *(u16x4v*)(ob + db * 16 + hi * 4) = o;
        }
        if (hi == 0)
            rbuf[(size_t)(ks * 8 + bh) * N_TOK + n] = m[f] + __builtin_amdgcn_logf(lt);
    }
}

// ---------------------------------------------------------------------------
// Kernel 3b: combine the 4 K-split quarters -> hT [b][n][c] bf16.
// thread -> (bh, n, 16-d block); 4 consecutive threads cover one n (coalesced).
__global__ __launch_bounds__(256) void attn_combine_kernel(
    const unsigned short* __restrict__ obuf, const float* __restrict__ rbuf,
    unsigned short* __restrict__ hT) {
    const int idx = blockIdx.x * 256 + threadIdx.x;
    const int dq  = (idx & 3) * 16;
    const int bhn = idx >> 2;                  // bh*N_TOK + n
    const int n   = bhn & (N_TOK - 1);
    const int bh  = bhn >> 12;
    float r[KSPLIT], M = -1e30f;
#pragma unroll
    for (int k = 0; k < KSPLIT; ++k) {
        r[k] = rbuf[(size_t)(k * 8 + bh) * N_TOK + n];
        M = fmaxf(M, r[k]);
    }
    float w[KSPLIT], tot = 0.f;
#pragma unroll
    for (int k = 0; k < KSPLIT; ++k) { w[k] = exp2_fast(r[k] - M); tot += w[k]; }
    const float inv = 1.f / tot;
    const int b = bh >> 2, head = bh & 3;
    unsigned short* dst = hT + ((size_t)b * N_TOK + n) * C_DIM + head * HD + dq;
#pragma unroll
    for (int c = 0; c < 2; ++c) {
        float a[8] = {};
#pragma unroll
        for (int k = 0; k < KSPLIT; ++k) {
            u16x8v v = *(const u16x8v*)(obuf + ((size_t)(k * 8 + bh) * N_TOK + n) * HD + dq + c * 8);
#pragma unroll
            for (int j = 0; j < 8; ++j) a[j] += w[k] * bf2f(v[j]);
        }
        u16x8v o;
#pragma unroll
        for (int j = 0; j < 8; ++j) o[j] = f2bf(a[j] * inv);
        *(u16x8v*)(dst + c * 8) = o;
    }
}

// ---------------------------------------------------------------------------
// Kernel 4: output projection + bias + residual, bf16 MFMA. Pure m97-style
// GEMM: BOTH operands staged via global_load_lds (bf16 weights + hT).
__global__ __launch_bounds__(256) void proj_kernel(
    const unsigned short* __restrict__ hT, const unsigned short* __restrict__ wpbf,
    const float* __restrict__ proj_b, const float* __restrict__ x,
    float* __restrict__ out) {
    __shared__ unsigned short Ws[64][64];  // [o][c] bf16, col-swizzled
    __shared__ unsigned short Hs[64][64];  // [n][c] bf16, col-swizzled
    const int n0 = blockIdx.x * 64;
    const int o0 = blockIdx.y * 64;
    const int b  = blockIdx.z;
    const int tid = threadIdx.x;
    const int lane = tid & 63, w = tid >> 6;
    const int lo = lane & 15, hi = lane >> 4;
    const int srow8 = lane >> 3, sblk = lane & 7;
    const int c16s = (sblk ^ srow8) * 8;
    int rcol[2];
#pragma unroll
    for (int c = 0; c < 2; ++c) rcol[c] = (((c * 4 + hi) ^ (lo & 7)) << 3);

    f32x4 acc[4] = {};
    for (int k0 = 0; k0 < C_DIM; k0 += 64) {
#pragma unroll
        for (int i = 0; i < 2; ++i) {
            int row = i * 32 + w * 8 + srow8;
            gload16(wpbf + (size_t)(o0 + row) * C_DIM + k0 + c16s, &Ws[i * 32 + w * 8][0]);
            gload16(hT + ((size_t)b * N_TOK + n0 + row) * C_DIM + k0 + c16s,
                    &Hs[i * 32 + w * 8][0]);
        }
        __syncthreads();   // drains DMA
#pragma unroll
        for (int ck = 0; ck < 2; ++ck) {
            bf16x8 aw = *(const bf16x8*)&Ws[w * 16 + lo][rcol[ck]];
#pragma unroll
            for (int nb = 0; nb < 4; ++nb)
                acc[nb] = __builtin_amdgcn_mfma_f32_16x16x32_bf16(
                    aw, *(const bf16x8*)&Hs[nb * 16 + lo][rcol[ck]], acc[nb], 0, 0, 0);
        }
        __syncthreads();
    }

#pragma unroll
    for (int nb = 0; nb < 4; ++nb) {
#pragma unroll
        for (int i = 0; i < 4; ++i) {
            int o = o0 + w * 16 + hi * 4 + i;
            size_t addr = ((size_t)b * C_DIM + o) * N_TOK + n0 + nb * 16 + lo;
            out[addr] = acc[nb][i] + proj_b[o] + x[addr];
        }
    }
}

// ---------------------------------------------------------------------------
extern "C" void kernel_launch(void* const* d_in, const int* in_sizes, int n_in,
                              void* d_out, int out_size, void* d_ws, size_t ws_size,
                              hipStream_t stream) {
    const float* x      = (const float*)d_in[0];
    const float* norm_w = (const float*)d_in[1];
    const float* norm_b = (const float*)d_in[2];
    const float* qkv_w  = (const float*)d_in[3];
    const float* qkv_b  = (const float*)d_in[4];
    const float* proj_w = (const float*)d_in[5];
    const float* proj_b = (const float*)d_in[6];
    float* out = (float*)d_out;

    // ws: partials f32[2048] (8KB) | wbf u16[262144] (512KB) | qkvb bf16 (12.6MB)
    //   | obuf bf16 [4][8][N][HD] (16.8MB) | rbuf f32 [4][8][N] (512KB) ~= 30.4MB
    // hT (4MB) aliases the dead q-plane of qkvb (attn completes before combine).
    float* partials = (float*)d_ws;
    unsigned short* wbf = (unsigned short*)(partials + 2048);
    unsigned short* qkvb = wbf + (NQKVW + NPROJW);
    unsigned short* hT = qkvb;  // q-plane reuse
    unsigned short* obuf = qkvb + (size_t)3 * B_DIM * HEADS * N_TOK * HD;
    float* rbuf = (float*)(obuf + (size_t)KSPLIT * B_DIM * HEADS * N_TOK * HD);
    const unsigned short* wqbf = wbf;
    const unsigned short* wpbf = wbf + NQKVW;

    gn_part_kernel<<<B_DIM * GROUPS * 64, 256, 0, stream>>>(x, qkv_w, proj_w, partials, wbf);
    qkv_gemm_kernel<<<dim3(N_TOK / 64, 3 * C_DIM / 64, B_DIM), 256, 0, stream>>>(
        x, partials, norm_w, norm_b, wqbf, qkv_b, qkvb);
    attn_kernel<<<(N_TOK / QBLK) * B_DIM * HEADS * KSPLIT, 512, 0, stream>>>(qkvb, obuf, rbuf);
    attn_combine_kernel<<<B_DIM * HEADS * N_TOK * 4 / 256, 256, 0, stream>>>(obuf, rbuf, hT);
    proj_kernel<<<dim3(N_TOK / 64, C_DIM / 64, B_DIM), 256, 0, stream>>>(
        hT, wpbf, proj_b, x, out);
}